// Round 1
// baseline (356.924 us; speedup 1.0000x reference)
//
#include <hip/hip_runtime.h>
#include <hip/hip_bf16.h>

// LinearAttention (efficient attention): B=4 N=4096 D_MODEL=1024 H=16 DH=64
// Pipeline: cvt -> GEMM1(qkv) -> qsoftmax -> ksoftmax stats -> context(K^T V)
//           -> attn GEMM (q*ctx) -> final GEMM (+bias, f32 out)

typedef unsigned short u16t;
typedef __bf16 bf16x8 __attribute__((ext_vector_type(8)));
typedef float f32x4 __attribute__((ext_vector_type(4)));

__device__ __forceinline__ u16t f2bf(float f) {
    union { float f; unsigned int u; } v; v.f = f;
    unsigned int r = v.u + 0x7fffu + ((v.u >> 16) & 1u);
    return (u16t)(r >> 16);
}
__device__ __forceinline__ float bf2f(u16t h) {
    union { unsigned int u; float f; } v; v.u = ((unsigned int)h) << 16;
    return v.f;
}

// ---------------- conversion kernels ----------------

__global__ void cvt_f32_bf16(const float* __restrict__ in, u16t* __restrict__ out, int n) {
    int i = (blockIdx.x * blockDim.x + threadIdx.x) * 4;
    int stride = gridDim.x * blockDim.x * 4;
    for (; i < n; i += stride) {
        float4 v = *(const float4*)(in + i);
        ushort4 o;
        o.x = f2bf(v.x); o.y = f2bf(v.y); o.z = f2bf(v.z); o.w = f2bf(v.w);
        *(ushort4*)(out + i) = o;
    }
}

// in [R][C] f32 -> out [C][R] bf16 (transpose + convert). grid (C/32, R/32), block (32,8)
__global__ void transpose_cvt(const float* __restrict__ in, u16t* __restrict__ out, int R, int C) {
    __shared__ float tile[32][33];
    int c0 = blockIdx.x * 32, r0 = blockIdx.y * 32;
    int tx = threadIdx.x, ty = threadIdx.y;
    for (int i = 0; i < 32; i += 8)
        tile[ty + i][tx] = in[(size_t)(r0 + ty + i) * C + c0 + tx];
    __syncthreads();
    for (int i = 0; i < 32; i += 8)
        out[(size_t)(c0 + ty + i) * R + r0 + tx] = f2bf(tile[tx][ty + i]);
}

// ---------------- generic bf16 GEMM: C = A * Bt^T ----------------
// A [M][K] bf16 row-major, Bt [N][K] bf16 row-major (pre-transposed B).
// 128x128 tile, BK=32, 256 threads (4 waves), each wave 64x64.
template<int OUTF32, int BIAS>
__global__ __launch_bounds__(256) void gemm_bt(const u16t* __restrict__ A, const u16t* __restrict__ Bt,
                                               void* __restrict__ Cout, const float* __restrict__ bias,
                                               int M, int N, int K) {
    __shared__ u16t lds_a[128 * 32];
    __shared__ u16t lds_b[128 * 32];
    const int t = threadIdx.x;
    const int lane = t & 63, w = t >> 6;
    const int wr = w >> 1, wc = w & 1;
    const int m0 = blockIdx.y * 128, n0 = blockIdx.x * 128;
    f32x4 acc[4][4] = {};

    for (int k0 = 0; k0 < K; k0 += 32) {
#pragma unroll
        for (int rep = 0; rep < 2; rep++) {
            int ff = t + rep * 256;          // 0..511
            int r = ff >> 2, q = ff & 3;     // 128 rows x 4 quads of 8 elems
            *(uint4*)(&lds_a[r * 32 + q * 8]) = *(const uint4*)(&A[(size_t)(m0 + r) * K + k0 + q * 8]);
            *(uint4*)(&lds_b[r * 32 + q * 8]) = *(const uint4*)(&Bt[(size_t)(n0 + r) * K + k0 + q * 8]);
        }
        __syncthreads();
        bf16x8 af[4], bfr[4];
#pragma unroll
        for (int mt = 0; mt < 4; mt++)
            af[mt] = *(const bf16x8*)(&lds_a[(wr * 64 + mt * 16 + (lane & 15)) * 32 + (lane >> 4) * 8]);
#pragma unroll
        for (int nt = 0; nt < 4; nt++)
            bfr[nt] = *(const bf16x8*)(&lds_b[(wc * 64 + nt * 16 + (lane & 15)) * 32 + (lane >> 4) * 8]);
#pragma unroll
        for (int mt = 0; mt < 4; mt++)
#pragma unroll
            for (int nt = 0; nt < 4; nt++)
                acc[mt][nt] = __builtin_amdgcn_mfma_f32_16x16x32_bf16(af[mt], bfr[nt], acc[mt][nt], 0, 0, 0);
        __syncthreads();
    }

#pragma unroll
    for (int mt = 0; mt < 4; mt++) {
        int row = m0 + wr * 64 + mt * 16 + ((lane >> 4) << 2);
#pragma unroll
        for (int nt = 0; nt < 4; nt++) {
            int col = n0 + wc * 64 + nt * 16 + (lane & 15);
            float bv = BIAS ? bias[col] : 0.f;
#pragma unroll
            for (int j = 0; j < 4; j++) {
                float v = acc[mt][nt][j] + bv;
                if (OUTF32) ((float*)Cout)[(size_t)(row + j) * N + col] = v;
                else        ((u16t*)Cout)[(size_t)(row + j) * N + col] = f2bf(v);
            }
        }
    }
}

// ---------------- q softmax (over d=64, in place, * SCALE) ----------------
// row id r in [0, B*N*H): bn = r>>4, h = r&15. 4 waves per block, wave per row.
__global__ void q_softmax(u16t* __restrict__ qkv) {
    int r = blockIdx.x * 4 + (threadIdx.x >> 6);
    int lane = threadIdx.x & 63;
    int bn = r >> 4, h = r & 15;
    size_t idx = (size_t)bn * 3072 + h * 64 + lane;
    float v = bf2f(qkv[idx]);
    float m = v;
#pragma unroll
    for (int off = 32; off; off >>= 1) m = fmaxf(m, __shfl_xor(m, off));
    float e = expf(v - m);
    float s = e;
#pragma unroll
    for (int off = 32; off; off >>= 1) s += __shfl_xor(s, off);
    qkv[idx] = f2bf(e / s * 0.125f);
}

// ---------------- k softmax stats (over n=4096) ----------------
// pass1: grid (64 bh, 16 chunks of 256 n), block 256: partial max/sum per (bh,chunk,d)
__global__ void k_softmax_p1(const u16t* __restrict__ qkv, float* __restrict__ pmax, float* __restrict__ psum) {
    int bh = blockIdx.x, chunk = blockIdx.y;
    int b = bh >> 4, h = bh & 15;
    int d = threadIdx.x & 63, sub = threadIdx.x >> 6;
    size_t base = (size_t)b * 4096 * 3072 + 1024 + h * 64 + d;
    float m = -1e30f, s = 0.f;
    for (int i = 0; i < 64; i++) {
        int n = chunk * 256 + sub + i * 4;
        float v = bf2f(qkv[base + (size_t)n * 3072]);
        if (v > m) { s = s * expf(m - v) + 1.f; m = v; }
        else s += expf(v - m);
    }
    __shared__ float sm[4][64], ss[4][64];
    sm[sub][d] = m; ss[sub][d] = s;
    __syncthreads();
    if (threadIdx.x < 64) {
        float M = sm[0][d];
        for (int i = 1; i < 4; i++) M = fmaxf(M, sm[i][d]);
        float S = 0.f;
        for (int i = 0; i < 4; i++) S += ss[i][d] * expf(sm[i][d] - M);
        int o = (bh * 16 + chunk) * 64 + d;
        pmax[o] = M; psum[o] = S;
    }
}

// pass2: grid 64 (bh), block 64 (d): combine 16 chunks -> gmax, ginv
__global__ void k_softmax_p2(const float* __restrict__ pmax, const float* __restrict__ psum,
                             float* __restrict__ gmax, float* __restrict__ ginv) {
    int bh = blockIdx.x, d = threadIdx.x;
    float M = -1e30f;
    for (int c = 0; c < 16; c++) M = fmaxf(M, pmax[(bh * 16 + c) * 64 + d]);
    float S = 0.f;
    for (int c = 0; c < 16; c++) S += psum[(bh * 16 + c) * 64 + d] * expf(pmax[(bh * 16 + c) * 64 + d] - M);
    gmax[bh * 64 + d] = M; ginv[bh * 64 + d] = 1.f / S;
}

// ---------------- context: ctxT[bh][e][d] = sum_n v[n][e] * ksoft[n][d] ----------------
// grid (64 bh, 32 chunks of 128 n), block 256. k-softmax normalize fused into staging.
__global__ __launch_bounds__(256) void context_kernel(const u16t* __restrict__ qkv,
                                                      const float* __restrict__ gmax, const float* __restrict__ ginv,
                                                      float* __restrict__ ctxT) {
    int bh = blockIdx.x, chunk = blockIdx.y;
    int b = bh >> 4, h = bh & 15;
    __shared__ u16t kT[64][136];  // [d][n], pad to 136 (272B rows, 16B aligned)
    __shared__ u16t vT[64][136];  // [e][n]
    int t = threadIdx.x, d = t & 63, g = t >> 6;
    float gm = gmax[bh * 64 + d], gi = ginv[bh * 64 + d];
    size_t rowbase = ((size_t)b * 4096 + chunk * 128) * 3072;
    for (int i = 0; i < 32; i++) {
        int n = g + i * 4;
        size_t ro = rowbase + (size_t)n * 3072 + h * 64 + d;
        float kv = bf2f(qkv[ro + 1024]);
        float vv = bf2f(qkv[ro + 2048]);
        kT[d][n] = f2bf(expf(kv - gm) * gi);
        vT[d][n] = f2bf(vv);
    }
    __syncthreads();
    int lane = t & 63, w = t >> 6;
    f32x4 acc[4] = {};
#pragma unroll
    for (int ks = 0; ks < 4; ks++) {
        bf16x8 a = *(const bf16x8*)(&vT[w * 16 + (lane & 15)][ks * 32 + (lane >> 4) * 8]);
#pragma unroll
        for (int ct = 0; ct < 4; ct++) {
            bf16x8 bb = *(const bf16x8*)(&kT[ct * 16 + (lane & 15)][ks * 32 + (lane >> 4) * 8]);
            acc[ct] = __builtin_amdgcn_mfma_f32_16x16x32_bf16(a, bb, acc[ct], 0, 0, 0);
        }
    }
#pragma unroll
    for (int ct = 0; ct < 4; ct++) {
        int e = w * 16 + ((lane >> 4) << 2);
        int dd = ct * 16 + (lane & 15);
#pragma unroll
        for (int j = 0; j < 4; j++)
            atomicAdd(&ctxT[(size_t)bh * 4096 + (e + j) * 64 + dd], acc[ct][j]);
    }
}

// ---------------- attn GEMM: attn[n][h*64+e] = sum_d qsoft[n][h*64+d] * ctxT[bh][e][d] ----------------
// grid (64 bh, 16 chunks of 256 n), block 256 (4 waves x 64 rows)
__global__ __launch_bounds__(256) void attn_gemm(const u16t* __restrict__ qkv, const float* __restrict__ ctxT,
                                                 u16t* __restrict__ attn) {
    int bh = blockIdx.x, chunk = blockIdx.y;
    int b = bh >> 4, h = bh & 15;
    __shared__ u16t q_lds[256][72];
    __shared__ u16t c_lds[64][72];
    int t = threadIdx.x;
#pragma unroll
    for (int i = 0; i < 16; i++) {
        int f = t + 256 * i;         // 0..4095
        int e = f >> 6, dd = f & 63;
        c_lds[e][dd] = f2bf(ctxT[(size_t)bh * 4096 + f]);
    }
    size_t qbase = ((size_t)b * 4096 + chunk * 256) * 3072 + h * 64;
#pragma unroll
    for (int i = 0; i < 8; i++) {
        int f = t + 256 * i;         // 0..2047 -> 256 rows x 8 quads
        int n = f >> 3, dg = f & 7;
        *(uint4*)(&q_lds[n][dg * 8]) = *(const uint4*)(&qkv[qbase + (size_t)n * 3072 + dg * 8]);
    }
    __syncthreads();
    int lane = t & 63, w = t >> 6;
    f32x4 acc[4][4] = {};
#pragma unroll
    for (int ks = 0; ks < 2; ks++) {
        bf16x8 af[4], bfr[4];
#pragma unroll
        for (int mt = 0; mt < 4; mt++)
            af[mt] = *(const bf16x8*)(&q_lds[w * 64 + mt * 16 + (lane & 15)][ks * 32 + (lane >> 4) * 8]);
#pragma unroll
        for (int et = 0; et < 4; et++)
            bfr[et] = *(const bf16x8*)(&c_lds[et * 16 + (lane & 15)][ks * 32 + (lane >> 4) * 8]);
#pragma unroll
        for (int mt = 0; mt < 4; mt++)
#pragma unroll
            for (int et = 0; et < 4; et++)
                acc[mt][et] = __builtin_amdgcn_mfma_f32_16x16x32_bf16(af[mt], bfr[et], acc[mt][et], 0, 0, 0);
    }
    size_t abase = (size_t)b * 4096 + chunk * 256;
#pragma unroll
    for (int mt = 0; mt < 4; mt++) {
        int n = w * 64 + mt * 16 + ((lane >> 4) << 2);
#pragma unroll
        for (int et = 0; et < 4; et++) {
            int e = et * 16 + (lane & 15);
#pragma unroll
            for (int j = 0; j < 4; j++)
                attn[(abase + n + j) * 1024 + h * 64 + e] = f2bf(acc[mt][et][j]);
        }
    }
}

// ---------------- launch ----------------

extern "C" void kernel_launch(void* const* d_in, const int* in_sizes, int n_in,
                              void* d_out, int out_size, void* d_ws, size_t ws_size,
                              hipStream_t stream) {
    const float* x     = (const float*)d_in[0];
    const float* w_qkv = (const float*)d_in[1];
    const float* w_out = (const float*)d_in[2];
    const float* b_out = (const float*)d_in[3];
    float* out = (float*)d_out;
    char* ws = (char*)d_ws;

    // ws layout (bytes)
    size_t o_xb    = 0;                       // 16384*1024*2 = 33554432 (reused as attn)
    size_t o_wqkvT = 33554432;                // 3072*1024*2  = 6291456
    size_t o_woutT = 39845888;                // 1024*1024*2  = 2097152
    size_t o_qkv   = 41943040;                // 16384*3072*2 = 100663296
    size_t o_ctx   = 142606336;               // 64*64*64*4   = 1048576
    size_t o_pmax  = 143654912;               // 64*16*64*4   = 262144
    size_t o_psum  = 143917056;               // 262144
    size_t o_gmax  = 144179200;               // 16384
    size_t o_ginv  = 144195584;               // 16384
    size_t needed  = 144211968;
    if (ws_size < needed) return;             // visible failure if ws too small

    u16t* xb     = (u16t*)(ws + o_xb);
    u16t* attnb  = (u16t*)(ws + o_xb);        // reuse (xb dead after GEMM1)
    u16t* wqkvT  = (u16t*)(ws + o_wqkvT);
    u16t* woutT  = (u16t*)(ws + o_woutT);
    u16t* qkvb   = (u16t*)(ws + o_qkv);
    float* ctxT  = (float*)(ws + o_ctx);
    float* pmax  = (float*)(ws + o_pmax);
    float* psum  = (float*)(ws + o_psum);
    float* gmax  = (float*)(ws + o_gmax);
    float* ginv  = (float*)(ws + o_ginv);

    cvt_f32_bf16<<<2048, 256, 0, stream>>>(x, xb, 16777216);
    transpose_cvt<<<dim3(96, 32), dim3(32, 8), 0, stream>>>(w_qkv, wqkvT, 1024, 3072);
    transpose_cvt<<<dim3(32, 32), dim3(32, 8), 0, stream>>>(w_out, woutT, 1024, 1024);

    gemm_bt<0, 0><<<dim3(24, 128), 256, 0, stream>>>(xb, wqkvT, qkvb, nullptr, 16384, 3072, 1024);

    q_softmax<<<65536, 256, 0, stream>>>(qkvb);
    k_softmax_p1<<<dim3(64, 16), 256, 0, stream>>>(qkvb, pmax, psum);
    k_softmax_p2<<<64, 64, 0, stream>>>(pmax, psum, gmax, ginv);

    hipMemsetAsync(ctxT, 0, 64 * 64 * 64 * 4, stream);
    context_kernel<<<dim3(64, 32), 256, 0, stream>>>(qkvb, gmax, ginv, ctxT);

    attn_gemm<<<dim3(64, 16), 256, 0, stream>>>(qkvb, ctxT, attnb);

    gemm_bt<1, 1><<<dim3(8, 128), 256, 0, stream>>>(attnb, woutT, out, b_out, 16384, 1024, 1024);
}

// Round 2
// 306.081 us; speedup vs baseline: 1.1661x; 1.1661x over previous
//
#include <hip/hip_runtime.h>
#include <hip/hip_bf16.h>

// LinearAttention (efficient attention): B=4 N=4096 D_MODEL=1024 H=16 DH=64
// Pipeline: cvt -> GEMM1(qkv, m97-style) -> ksoftmax stats -> context(K^T V, +p2 fused)
//           -> attn GEMM (q-softmax fused + q*ctx) -> final GEMM (+bias, f32 out)

typedef unsigned short u16t;
typedef __bf16 bf16x8 __attribute__((ext_vector_type(8)));
typedef float f32x4 __attribute__((ext_vector_type(4)));
typedef unsigned short ushort8 __attribute__((ext_vector_type(8)));

__device__ __forceinline__ u16t f2bf(float f) {
    union { float f; unsigned int u; } v; v.f = f;
    unsigned int r = v.u + 0x7fffu + ((v.u >> 16) & 1u);
    return (u16t)(r >> 16);
}
__device__ __forceinline__ float bf2f(u16t h) {
    union { unsigned int u; float f; } v; v.u = ((unsigned int)h) << 16;
    return v.f;
}

#define GLOAD_LDS16(gptr, lptr) \
    __builtin_amdgcn_global_load_lds((const __attribute__((address_space(1))) unsigned int*)(gptr), \
                                     (__attribute__((address_space(3))) unsigned int*)(lptr), 16, 0, 0)

// ---------------- conversion kernels ----------------

__global__ void cvt_f32_bf16(const float* __restrict__ in, u16t* __restrict__ out, int n) {
    int i = (blockIdx.x * blockDim.x + threadIdx.x) * 4;
    int stride = gridDim.x * blockDim.x * 4;
    for (; i < n; i += stride) {
        float4 v = *(const float4*)(in + i);
        ushort4 o;
        o.x = f2bf(v.x); o.y = f2bf(v.y); o.z = f2bf(v.z); o.w = f2bf(v.w);
        *(ushort4*)(out + i) = o;
    }
}

// in [R][C] f32 -> out [C][R] bf16 (transpose + convert). grid (C/32, R/32), block (32,8)
__global__ void transpose_cvt(const float* __restrict__ in, u16t* __restrict__ out, int R, int C) {
    __shared__ float tile[32][33];
    int c0 = blockIdx.x * 32, r0 = blockIdx.y * 32;
    int tx = threadIdx.x, ty = threadIdx.y;
    for (int i = 0; i < 32; i += 8)
        tile[ty + i][tx] = in[(size_t)(r0 + ty + i) * C + c0 + tx];
    __syncthreads();
    for (int i = 0; i < 32; i += 8)
        out[(size_t)(c0 + ty + i) * R + r0 + tx] = f2bf(tile[tx][ty + i]);
}

// ---------------- generic bf16 GEMM: C = A * Bt^T (m97 structure) ----------------
// A [M][K] bf16 row-major, Bt [N][K] bf16 row-major (pre-transposed B).
// 128x128 tile, BK=32, 256 threads (4 waves), each wave 64x64.
// Staging via global_load_lds width=16: thread t's 16B lands at LDS byte t*16
// (wave-uniform base + lane*16), matching rows r=t>>2, quad q=t&3 of the linear
// [128][32] tile.
template<int OUTF32, int BIAS>
__global__ __launch_bounds__(256) void gemm_bt(const u16t* __restrict__ A, const u16t* __restrict__ Bt,
                                               void* __restrict__ Cout, const float* __restrict__ bias,
                                               int M, int N, int K) {
    __shared__ __align__(16) u16t lds_a[128 * 32];
    __shared__ __align__(16) u16t lds_b[128 * 32];
    const int t = threadIdx.x;
    const int lane = t & 63, w = t >> 6;
    const int wr = w >> 1, wc = w & 1;
    const int m0 = blockIdx.y * 128, n0 = blockIdx.x * 128;
    const int r0 = t >> 2, q0 = t & 3;
    const u16t* pa = &A[(size_t)(m0 + r0) * K + q0 * 8];
    const u16t* pb = &Bt[(size_t)(n0 + r0) * K + q0 * 8];
    const int lo = w * 512;                  // u16 units; wave base; rep1 adds 2048
    f32x4 acc[4][4] = {};

    for (int k0 = 0; k0 < K; k0 += 32) {
        GLOAD_LDS16(pa,           &lds_a[lo]);
        GLOAD_LDS16(pa + 64 * (size_t)K, &lds_a[2048 + lo]);
        GLOAD_LDS16(pb,           &lds_b[lo]);
        GLOAD_LDS16(pb + 64 * (size_t)K, &lds_b[2048 + lo]);
        pa += 32; pb += 32;
        __syncthreads();
        bf16x8 af[4], bfr[4];
#pragma unroll
        for (int mt = 0; mt < 4; mt++)
            af[mt] = *(const bf16x8*)(&lds_a[(wr * 64 + mt * 16 + (lane & 15)) * 32 + (lane >> 4) * 8]);
#pragma unroll
        for (int nt = 0; nt < 4; nt++)
            bfr[nt] = *(const bf16x8*)(&lds_b[(wc * 64 + nt * 16 + (lane & 15)) * 32 + (lane >> 4) * 8]);
#pragma unroll
        for (int mt = 0; mt < 4; mt++)
#pragma unroll
            for (int nt = 0; nt < 4; nt++)
                acc[mt][nt] = __builtin_amdgcn_mfma_f32_16x16x32_bf16(af[mt], bfr[nt], acc[mt][nt], 0, 0, 0);
        __syncthreads();
    }

#pragma unroll
    for (int mt = 0; mt < 4; mt++) {
        int row = m0 + wr * 64 + mt * 16 + ((lane >> 4) << 2);
#pragma unroll
        for (int nt = 0; nt < 4; nt++) {
            int col = n0 + wc * 64 + nt * 16 + (lane & 15);
            float bv = BIAS ? bias[col] : 0.f;
#pragma unroll
            for (int j = 0; j < 4; j++) {
                float v = acc[mt][nt][j] + bv;
                if (OUTF32) ((float*)Cout)[(size_t)(row + j) * N + col] = v;
                else        ((u16t*)Cout)[(size_t)(row + j) * N + col] = f2bf(v);
            }
        }
    }
}

// ---------------- k softmax stats (over n=4096) ----------------
// pass1: grid (64 bh, 16 chunks of 256 n), block 256: partial max/sum per (bh,chunk,d)
__global__ void k_softmax_p1(const u16t* __restrict__ qkv, float* __restrict__ pmax, float* __restrict__ psum) {
    int bh = blockIdx.x, chunk = blockIdx.y;
    int b = bh >> 4, h = bh & 15;
    int d = threadIdx.x & 63, sub = threadIdx.x >> 6;
    size_t base = (size_t)b * 4096 * 3072 + 1024 + h * 64 + d;
    float m = -1e30f, s = 0.f;
    for (int i = 0; i < 64; i++) {
        int n = chunk * 256 + sub + i * 4;
        float v = bf2f(qkv[base + (size_t)n * 3072]);
        if (v > m) { s = s * expf(m - v) + 1.f; m = v; }
        else s += expf(v - m);
    }
    __shared__ float sm[4][64], ss[4][64];
    sm[sub][d] = m; ss[sub][d] = s;
    __syncthreads();
    if (threadIdx.x < 64) {
        float M = sm[0][d];
        for (int i = 1; i < 4; i++) M = fmaxf(M, sm[i][d]);
        float S = 0.f;
        for (int i = 0; i < 4; i++) S += ss[i][d] * expf(sm[i][d] - M);
        int o = (bh * 16 + chunk) * 64 + d;
        pmax[o] = M; psum[o] = S;
    }
}

// ---------------- context: ctxT[bh][e][d] = sum_n v[n][e] * ksoft[n][d] ----------------
// grid (64 bh, 8 chunks of 512 n), block 256. p2 (global stats combine) fused;
// k-softmax normalize fused into staging. 4 sub-chunks accumulated in reg -> 1 atomic pass.
__global__ __launch_bounds__(256) void context_kernel(const u16t* __restrict__ qkv,
                                                      const float* __restrict__ pmax, const float* __restrict__ psum,
                                                      float* __restrict__ ctxT) {
    int bh = blockIdx.x, chunk = blockIdx.y;
    int b = bh >> 4, h = bh & 15;
    __shared__ u16t kT[64][136];  // [d][n], pad to 136
    __shared__ u16t vT[64][136];  // [e][n]
    __shared__ float s_gm[64], s_gi[64];
    int t = threadIdx.x;
    if (t < 64) {
        float M = -1e30f;
        for (int c = 0; c < 16; c++) M = fmaxf(M, pmax[(bh * 16 + c) * 64 + t]);
        float S = 0.f;
        for (int c = 0; c < 16; c++) S += psum[(bh * 16 + c) * 64 + t] * expf(pmax[(bh * 16 + c) * 64 + t] - M);
        s_gm[t] = M; s_gi[t] = 1.f / S;
    }
    __syncthreads();
    int d = t & 63, g = t >> 6;
    float gm = s_gm[d], gi = s_gi[d];
    int lane = t & 63, w = t >> 6;
    f32x4 acc[4] = {};
    for (int sub = 0; sub < 4; sub++) {
        size_t rowbase = ((size_t)b * 4096 + chunk * 512 + sub * 128) * 3072;
        for (int i = 0; i < 32; i++) {
            int n = g + i * 4;
            size_t ro = rowbase + (size_t)n * 3072 + h * 64 + d;
            kT[d][n] = f2bf(expf(bf2f(qkv[ro + 1024]) - gm) * gi);
            vT[d][n] = qkv[ro + 2048];
        }
        __syncthreads();
#pragma unroll
        for (int ks = 0; ks < 4; ks++) {
            bf16x8 a = *(const bf16x8*)(&vT[w * 16 + (lane & 15)][ks * 32 + (lane >> 4) * 8]);
#pragma unroll
            for (int ct = 0; ct < 4; ct++) {
                bf16x8 bb = *(const bf16x8*)(&kT[ct * 16 + (lane & 15)][ks * 32 + (lane >> 4) * 8]);
                acc[ct] = __builtin_amdgcn_mfma_f32_16x16x32_bf16(a, bb, acc[ct], 0, 0, 0);
            }
        }
        __syncthreads();
    }
#pragma unroll
    for (int ct = 0; ct < 4; ct++) {
        int e = w * 16 + ((lane >> 4) << 2);
        int dd = ct * 16 + (lane & 15);
#pragma unroll
        for (int j = 0; j < 4; j++)
            atomicAdd(&ctxT[(size_t)bh * 4096 + (e + j) * 64 + dd], acc[ct][j]);
    }
}

// ---------------- attn GEMM (q-softmax fused): attn[n][h*64+e] = sum_d qsm[n][d] * ctxT[bh][e][d] ----
// grid (64 bh, 16 chunks of 256 n), block 256 (4 waves x 64 rows)
__global__ __launch_bounds__(256) void attn_gemm(const u16t* __restrict__ qkv, const float* __restrict__ ctxT,
                                                 u16t* __restrict__ attn) {
    int bh = blockIdx.x, chunk = blockIdx.y;
    int b = bh >> 4, h = bh & 15;
    __shared__ u16t q_lds[256][72];
    __shared__ u16t c_lds[64][72];
    int t = threadIdx.x;
#pragma unroll
    for (int i = 0; i < 16; i++) {
        int f = t + 256 * i;         // 0..4095
        int e = f >> 6, dd = f & 63;
        c_lds[e][dd] = f2bf(ctxT[(size_t)bh * 4096 + f]);
    }
    size_t qbase = ((size_t)b * 4096 + chunk * 256) * 3072 + h * 64;
#pragma unroll
    for (int i = 0; i < 8; i++) {
        int f = t + 256 * i;         // 0..2047 -> 256 rows x 8 quads
        int n = f >> 3, dg = f & 7;
        *(uint4*)(&q_lds[n][dg * 8]) = *(const uint4*)(&qkv[qbase + (size_t)n * 3072 + dg * 8]);
    }
    __syncthreads();
    // fused q softmax over d=64: one thread per row (256 threads = 256 rows)
    {
        ushort8 ch[8];
#pragma unroll
        for (int c = 0; c < 8; c++) ch[c] = *(const ushort8*)(&q_lds[t][c * 8]);
        float m = -1e30f;
#pragma unroll
        for (int c = 0; c < 8; c++)
#pragma unroll
            for (int j = 0; j < 8; j++) m = fmaxf(m, bf2f(ch[c][j]));
        float s = 0.f;
#pragma unroll
        for (int c = 0; c < 8; c++)
#pragma unroll
            for (int j = 0; j < 8; j++) s += expf(bf2f(ch[c][j]) - m);
        float inv = 0.125f / s;   // fold SCALE
#pragma unroll
        for (int c = 0; c < 8; c++) {
            ushort8 o;
#pragma unroll
            for (int j = 0; j < 8; j++) o[j] = f2bf(expf(bf2f(ch[c][j]) - m) * inv);
            *(ushort8*)(&q_lds[t][c * 8]) = o;
        }
    }
    __syncthreads();
    int lane = t & 63, w = t >> 6;
    f32x4 acc[4][4] = {};
#pragma unroll
    for (int ks = 0; ks < 2; ks++) {
        bf16x8 af[4], bfr[4];
#pragma unroll
        for (int mt = 0; mt < 4; mt++)
            af[mt] = *(const bf16x8*)(&q_lds[w * 64 + mt * 16 + (lane & 15)][ks * 32 + (lane >> 4) * 8]);
#pragma unroll
        for (int et = 0; et < 4; et++)
            bfr[et] = *(const bf16x8*)(&c_lds[et * 16 + (lane & 15)][ks * 32 + (lane >> 4) * 8]);
#pragma unroll
        for (int mt = 0; mt < 4; mt++)
#pragma unroll
            for (int et = 0; et < 4; et++)
                acc[mt][et] = __builtin_amdgcn_mfma_f32_16x16x32_bf16(af[mt], bfr[et], acc[mt][et], 0, 0, 0);
    }
    size_t abase = (size_t)b * 4096 + chunk * 256;
#pragma unroll
    for (int mt = 0; mt < 4; mt++) {
        int n = w * 64 + mt * 16 + ((lane >> 4) << 2);
#pragma unroll
        for (int et = 0; et < 4; et++) {
            int e = et * 16 + (lane & 15);
#pragma unroll
            for (int j = 0; j < 4; j++)
                attn[(abase + n + j) * 1024 + h * 64 + e] = f2bf(acc[mt][et][j]);
        }
    }
}

// ---------------- launch ----------------

extern "C" void kernel_launch(void* const* d_in, const int* in_sizes, int n_in,
                              void* d_out, int out_size, void* d_ws, size_t ws_size,
                              hipStream_t stream) {
    const float* x     = (const float*)d_in[0];
    const float* w_qkv = (const float*)d_in[1];
    const float* w_out = (const float*)d_in[2];
    const float* b_out = (const float*)d_in[3];
    float* out = (float*)d_out;
    char* ws = (char*)d_ws;

    // ws layout (bytes)
    size_t o_xb    = 0;                       // 16384*1024*2 = 33554432 (reused as attn)
    size_t o_wqkvT = 33554432;                // 3072*1024*2  = 6291456
    size_t o_woutT = 39845888;                // 1024*1024*2  = 2097152
    size_t o_qkv   = 41943040;                // 16384*3072*2 = 100663296
    size_t o_ctx   = 142606336;               // 64*64*64*4   = 1048576
    size_t o_pmax  = 143654912;               // 64*16*64*4   = 262144
    size_t o_psum  = 143917056;               // 262144
    size_t needed  = 144179200;
    if (ws_size < needed) return;             // visible failure if ws too small

    u16t* xb     = (u16t*)(ws + o_xb);
    u16t* attnb  = (u16t*)(ws + o_xb);        // reuse (xb dead after GEMM1)
    u16t* wqkvT  = (u16t*)(ws + o_wqkvT);
    u16t* woutT  = (u16t*)(ws + o_woutT);
    u16t* qkvb   = (u16t*)(ws + o_qkv);
    float* ctxT  = (float*)(ws + o_ctx);
    float* pmax  = (float*)(ws + o_pmax);
    float* psum  = (float*)(ws + o_psum);

    cvt_f32_bf16<<<2048, 256, 0, stream>>>(x, xb, 16777216);
    transpose_cvt<<<dim3(96, 32), dim3(32, 8), 0, stream>>>(w_qkv, wqkvT, 1024, 3072);
    transpose_cvt<<<dim3(32, 32), dim3(32, 8), 0, stream>>>(w_out, woutT, 1024, 1024);

    gemm_bt<0, 0><<<dim3(24, 128), 256, 0, stream>>>(xb, wqkvT, qkvb, nullptr, 16384, 3072, 1024);

    k_softmax_p1<<<dim3(64, 16), 256, 0, stream>>>(qkvb, pmax, psum);

    hipMemsetAsync(ctxT, 0, 64 * 64 * 64 * 4, stream);
    context_kernel<<<dim3(64, 8), 256, 0, stream>>>(qkvb, pmax, psum, ctxT);

    attn_gemm<<<dim3(64, 16), 256, 0, stream>>>(qkvb, ctxT, attnb);

    gemm_bt<1, 1><<<dim3(8, 128), 256, 0, stream>>>(attnb, woutT, out, b_out, 16384, 1024, 1024);
}

// Round 3
// 251.121 us; speedup vs baseline: 1.4213x; 1.2189x over previous
//
#include <hip/hip_runtime.h>
#include <hip/hip_bf16.h>

// LinearAttention (efficient attention): B=4 N=4096 D_MODEL=1024 H=16 DH=64
// Pipeline: cvt -> GEMM1(qkv, 256^2 8-phase) -> ksoftmax stats -> context(K^T V, +p2 fused)
//           -> attn GEMM (q-softmax fused + q*ctx) -> final GEMM (256^2 8-phase, +bias, f32)

typedef unsigned short u16t;
typedef __bf16 bf16x8 __attribute__((ext_vector_type(8)));
typedef float f32x4 __attribute__((ext_vector_type(4)));
typedef unsigned short ushort8 __attribute__((ext_vector_type(8)));

__device__ __forceinline__ u16t f2bf(float f) {
    union { float f; unsigned int u; } v; v.f = f;
    unsigned int r = v.u + 0x7fffu + ((v.u >> 16) & 1u);
    return (u16t)(r >> 16);
}
__device__ __forceinline__ float bf2f(u16t h) {
    union { unsigned int u; float f; } v; v.u = ((unsigned int)h) << 16;
    return v.f;
}

#define GLOAD_LDS16(gptr, lptr) \
    __builtin_amdgcn_global_load_lds((const __attribute__((address_space(1))) unsigned int*)(gptr), \
                                     (__attribute__((address_space(3))) unsigned int*)(lptr), 16, 0, 0)

// ---------------- conversion kernels ----------------

__global__ void cvt_f32_bf16(const float* __restrict__ in, u16t* __restrict__ out, int n) {
    int i = (blockIdx.x * blockDim.x + threadIdx.x) * 4;
    int stride = gridDim.x * blockDim.x * 4;
    for (; i < n; i += stride) {
        float4 v = *(const float4*)(in + i);
        ushort4 o;
        o.x = f2bf(v.x); o.y = f2bf(v.y); o.z = f2bf(v.z); o.w = f2bf(v.w);
        *(ushort4*)(out + i) = o;
    }
}

// in [R][C] f32 -> out [C][R] bf16 (transpose + convert). grid (C/32, R/32), block (32,8)
__global__ void transpose_cvt(const float* __restrict__ in, u16t* __restrict__ out, int R, int C) {
    __shared__ float tile[32][33];
    int c0 = blockIdx.x * 32, r0 = blockIdx.y * 32;
    int tx = threadIdx.x, ty = threadIdx.y;
    for (int i = 0; i < 32; i += 8)
        tile[ty + i][tx] = in[(size_t)(r0 + ty + i) * C + c0 + tx];
    __syncthreads();
    for (int i = 0; i < 32; i += 8)
        out[(size_t)(c0 + ty + i) * R + r0 + tx] = f2bf(tile[tx][ty + i]);
}

// ---------------- 256x256 8-phase bf16 GEMM: C = A * Bt^T ----------------
// A [M][K] bf16 row-major, Bt [N][K] bf16 row-major (pre-transposed B).
// 512 threads = 8 waves (2 M x 4 N), per-wave output 128x64, BK=64, LDS 128KB dbuf.
// T2 st-swizzle: element (row,col) of a tile stored at u16 idx (row*64 + col) ^ ((row&7)<<3).
// Staged via global_load_lds (linear dest) with inverse-permuted per-lane global source.
// Schedule: per K-tile 4 quadrant phases x 16 MFMA; all 8 stages of tile t+1 issued at
// phase 1 into the other buffer; vmcnt(0) only at phase-4 end (~3 phases of slack).
template<int OUTF32, int BIAS>
__global__ __launch_bounds__(512, 2) void gemm256(const u16t* __restrict__ A, const u16t* __restrict__ Bt,
                                                  void* __restrict__ Cout, const float* __restrict__ bias,
                                                  int M, int N, int K, int NBX) {
    __shared__ __align__(16) u16t lds[65536];   // 128 KB: [buf][A 16384 | B 16384]
    const int t = threadIdx.x;
    const int l = t & 63, w = t >> 6;
    const int wm = w >> 2, wn = w & 3;

    // XCD-aware bijective swizzle (gridDim.x % 8 == 0)
    int cpx = gridDim.x >> 3;
    int wg = ((int)blockIdx.x & 7) * cpx + ((int)blockIdx.x >> 3);
    int bx = wg % NBX, by = wg / NBX;
    const int m0 = by * 256, n0 = bx * 256;
    const int NT = K >> 6;

    // fragment read addressing (u16 units, swizzle folded per-thread)
    const int colk0 = (((l >> 4) * 8) ^ ((l & 7) * 8));
    const int colk1 = colk0 ^ 32;
    const int abase = (wm * 128 + (l & 15)) * 64;
    const int bbase = (wn * 64 + (l & 15)) * 64;

    // staging addressing: lane l covers window-row (l>>3), source col chunk (l^(l>>3))&7
    const int rowoff = w * 8 + (l >> 3);
    const int coloff = ((l ^ (l >> 3)) & 7) * 8;
    const u16t* pa_stage = A  + (size_t)(m0 + rowoff) * K + coloff;
    const u16t* pb_stage = Bt + (size_t)(n0 + rowoff) * K + coloff;
    const int stage_off = w * 512;   // u16; + i*4096 per 64-row group

#define STAGE_TILE(kto, pdst) do { \
    const u16t* sA_ = pa_stage + (size_t)(kto) * 64; \
    const u16t* sB_ = pb_stage + (size_t)(kto) * 64; \
    u16t* dA_ = &lds[(pdst) * 32768 + stage_off]; \
    u16t* dB_ = &lds[(pdst) * 32768 + 16384 + stage_off]; \
    GLOAD_LDS16(sA_,                    dA_);         \
    GLOAD_LDS16(sA_ + (size_t)64  * K, dA_ + 4096);  \
    GLOAD_LDS16(sA_ + (size_t)128 * K, dA_ + 8192);  \
    GLOAD_LDS16(sA_ + (size_t)192 * K, dA_ + 12288); \
    GLOAD_LDS16(sB_,                    dB_);         \
    GLOAD_LDS16(sB_ + (size_t)64  * K, dB_ + 4096);  \
    GLOAD_LDS16(sB_ + (size_t)128 * K, dB_ + 8192);  \
    GLOAD_LDS16(sB_ + (size_t)192 * K, dB_ + 12288); \
} while (0)

    f32x4 acc[8][4] = {};

    // prologue: stage tile 0 -> buf 0
    STAGE_TILE(0, 0);
    asm volatile("s_waitcnt vmcnt(0)" ::: "memory");
    __builtin_amdgcn_s_barrier();

    for (int kt = 0; kt < NT; ++kt) {
        const int p = kt & 1;
        const u16t* lA = &lds[p * 32768];
        const u16t* lB = &lds[p * 32768 + 16384];
        const bool stage_next = (kt + 1 < NT);
        bf16x8 bfr[4][2];
#pragma unroll
        for (int q = 0; q < 4; ++q) {
            bf16x8 af[2][2];
#pragma unroll
            for (int dm = 0; dm < 2; ++dm) {
                af[dm][0] = *(const bf16x8*)&lA[abase + (q * 2 + dm) * 1024 + colk0];
                af[dm][1] = *(const bf16x8*)&lA[abase + (q * 2 + dm) * 1024 + colk1];
            }
            if (q == 0) {
#pragma unroll
                for (int ni = 0; ni < 4; ++ni) {
                    bfr[ni][0] = *(const bf16x8*)&lB[bbase + ni * 1024 + colk0];
                    bfr[ni][1] = *(const bf16x8*)&lB[bbase + ni * 1024 + colk1];
                }
                if (stage_next) STAGE_TILE(kt + 1, p ^ 1);
            }
            __builtin_amdgcn_s_barrier();
            asm volatile("s_waitcnt lgkmcnt(0)" ::: "memory");
            __builtin_amdgcn_sched_barrier(0);
            __builtin_amdgcn_s_setprio(1);
#pragma unroll
            for (int dm = 0; dm < 2; ++dm)
#pragma unroll
                for (int ni = 0; ni < 4; ++ni)
#pragma unroll
                    for (int kk = 0; kk < 2; ++kk)
                        acc[q * 2 + dm][ni] = __builtin_amdgcn_mfma_f32_16x16x32_bf16(
                            af[dm][kk], bfr[ni][kk], acc[q * 2 + dm][ni], 0, 0, 0);
            __builtin_amdgcn_s_setprio(0);
            if (q == 3 && stage_next)
                asm volatile("s_waitcnt vmcnt(0)" ::: "memory");
            __builtin_amdgcn_s_barrier();
        }
    }
#undef STAGE_TILE

    // epilogue
#pragma unroll
    for (int mi = 0; mi < 8; ++mi) {
        int row = m0 + wm * 128 + mi * 16 + ((l >> 4) << 2);
#pragma unroll
        for (int ni = 0; ni < 4; ++ni) {
            int col = n0 + wn * 64 + ni * 16 + (l & 15);
            float bv = BIAS ? bias[col] : 0.f;
#pragma unroll
            for (int j = 0; j < 4; ++j) {
                float v = acc[mi][ni][j] + bv;
                if (OUTF32) ((float*)Cout)[(size_t)(row + j) * N + col] = v;
                else        ((u16t*)Cout)[(size_t)(row + j) * N + col] = f2bf(v);
            }
        }
    }
}

// ---------------- k softmax stats (over n=4096) ----------------
// pass1: grid (64 bh, 16 chunks of 256 n), block 256: partial max/sum per (bh,chunk,d)
__global__ void k_softmax_p1(const u16t* __restrict__ qkv, float* __restrict__ pmax, float* __restrict__ psum) {
    int bh = blockIdx.x, chunk = blockIdx.y;
    int b = bh >> 4, h = bh & 15;
    int d = threadIdx.x & 63, sub = threadIdx.x >> 6;
    size_t base = (size_t)b * 4096 * 3072 + 1024 + h * 64 + d;
    float m = -1e30f, s = 0.f;
    for (int i = 0; i < 64; i++) {
        int n = chunk * 256 + sub + i * 4;
        float v = bf2f(qkv[base + (size_t)n * 3072]);
        if (v > m) { s = s * expf(m - v) + 1.f; m = v; }
        else s += expf(v - m);
    }
    __shared__ float sm[4][64], ss[4][64];
    sm[sub][d] = m; ss[sub][d] = s;
    __syncthreads();
    if (threadIdx.x < 64) {
        float M = sm[0][d];
        for (int i = 1; i < 4; i++) M = fmaxf(M, sm[i][d]);
        float S = 0.f;
        for (int i = 0; i < 4; i++) S += ss[i][d] * expf(sm[i][d] - M);
        int o = (bh * 16 + chunk) * 64 + d;
        pmax[o] = M; psum[o] = S;
    }
}

// ---------------- context: ctxT[bh][e][d] = sum_n v[n][e] * ksoft[n][d] ----------------
// grid (64 bh, 8 chunks of 512 n), block 256. p2 (global stats combine) fused;
// k-softmax normalize fused into staging. 4 sub-chunks accumulated in reg -> 1 atomic pass.
__global__ __launch_bounds__(256) void context_kernel(const u16t* __restrict__ qkv,
                                                      const float* __restrict__ pmax, const float* __restrict__ psum,
                                                      float* __restrict__ ctxT) {
    int bh = blockIdx.x, chunk = blockIdx.y;
    int b = bh >> 4, h = bh & 15;
    __shared__ u16t kT[64][136];  // [d][n], pad to 136
    __shared__ u16t vT[64][136];  // [e][n]
    __shared__ float s_gm[64], s_gi[64];
    int t = threadIdx.x;
    if (t < 64) {
        float M = -1e30f;
        for (int c = 0; c < 16; c++) M = fmaxf(M, pmax[(bh * 16 + c) * 64 + t]);
        float S = 0.f;
        for (int c = 0; c < 16; c++) S += psum[(bh * 16 + c) * 64 + t] * expf(pmax[(bh * 16 + c) * 64 + t] - M);
        s_gm[t] = M; s_gi[t] = 1.f / S;
    }
    __syncthreads();
    int d = t & 63, g = t >> 6;
    float gm = s_gm[d], gi = s_gi[d];
    int lane = t & 63, w = t >> 6;
    f32x4 acc[4] = {};
    for (int sub = 0; sub < 4; sub++) {
        size_t rowbase = ((size_t)b * 4096 + chunk * 512 + sub * 128) * 3072;
        for (int i = 0; i < 32; i++) {
            int n = g + i * 4;
            size_t ro = rowbase + (size_t)n * 3072 + h * 64 + d;
            kT[d][n] = f2bf(expf(bf2f(qkv[ro + 1024]) - gm) * gi);
            vT[d][n] = qkv[ro + 2048];
        }
        __syncthreads();
#pragma unroll
        for (int ks = 0; ks < 4; ks++) {
            bf16x8 a = *(const bf16x8*)(&vT[w * 16 + (lane & 15)][ks * 32 + (lane >> 4) * 8]);
#pragma unroll
            for (int ct = 0; ct < 4; ct++) {
                bf16x8 bb = *(const bf16x8*)(&kT[ct * 16 + (lane & 15)][ks * 32 + (lane >> 4) * 8]);
                acc[ct] = __builtin_amdgcn_mfma_f32_16x16x32_bf16(a, bb, acc[ct], 0, 0, 0);
            }
        }
        __syncthreads();
    }
#pragma unroll
    for (int ct = 0; ct < 4; ct++) {
        int e = w * 16 + ((lane >> 4) << 2);
        int dd = ct * 16 + (lane & 15);
#pragma unroll
        for (int j = 0; j < 4; j++)
            atomicAdd(&ctxT[(size_t)bh * 4096 + (e + j) * 64 + dd], acc[ct][j]);
    }
}

// ---------------- attn GEMM (q-softmax fused): attn[n][h*64+e] = sum_d qsm[n][d] * ctxT[bh][e][d] ----
// grid (64 bh, 16 chunks of 256 n), block 256 (4 waves x 64 rows)
__global__ __launch_bounds__(256) void attn_gemm(const u16t* __restrict__ qkv, const float* __restrict__ ctxT,
                                                 u16t* __restrict__ attn) {
    int bh = blockIdx.x, chunk = blockIdx.y;
    int b = bh >> 4, h = bh & 15;
    __shared__ u16t q_lds[256][72];
    __shared__ u16t c_lds[64][72];
    int t = threadIdx.x;
#pragma unroll
    for (int i = 0; i < 16; i++) {
        int f = t + 256 * i;         // 0..4095
        int e = f >> 6, dd = f & 63;
        c_lds[e][dd] = f2bf(ctxT[(size_t)bh * 4096 + f]);
    }
    size_t qbase = ((size_t)b * 4096 + chunk * 256) * 3072 + h * 64;
#pragma unroll
    for (int i = 0; i < 8; i++) {
        int f = t + 256 * i;         // 0..2047 -> 256 rows x 8 quads
        int n = f >> 3, dg = f & 7;
        *(uint4*)(&q_lds[n][dg * 8]) = *(const uint4*)(&qkv[qbase + (size_t)n * 3072 + dg * 8]);
    }
    __syncthreads();
    // fused q softmax over d=64: one thread per row (256 threads = 256 rows)
    {
        ushort8 ch[8];
#pragma unroll
        for (int c = 0; c < 8; c++) ch[c] = *(const ushort8*)(&q_lds[t][c * 8]);
        float m = -1e30f;
#pragma unroll
        for (int c = 0; c < 8; c++)
#pragma unroll
            for (int j = 0; j < 8; j++) m = fmaxf(m, bf2f(ch[c][j]));
        float s = 0.f;
#pragma unroll
        for (int c = 0; c < 8; c++)
#pragma unroll
            for (int j = 0; j < 8; j++) s += expf(bf2f(ch[c][j]) - m);
        float inv = 0.125f / s;   // fold SCALE
#pragma unroll
        for (int c = 0; c < 8; c++) {
            ushort8 o;
#pragma unroll
            for (int j = 0; j < 8; j++) o[j] = f2bf(expf(bf2f(ch[c][j]) - m) * inv);
            *(ushort8*)(&q_lds[t][c * 8]) = o;
        }
    }
    __syncthreads();
    int lane = t & 63, w = t >> 6;
    f32x4 acc[4][4] = {};
#pragma unroll
    for (int ks = 0; ks < 2; ks++) {
        bf16x8 af[4], bfr[4];
#pragma unroll
        for (int mt = 0; mt < 4; mt++)
            af[mt] = *(const bf16x8*)(&q_lds[w * 64 + mt * 16 + (lane & 15)][ks * 32 + (lane >> 4) * 8]);
#pragma unroll
        for (int et = 0; et < 4; et++)
            bfr[et] = *(const bf16x8*)(&c_lds[et * 16 + (lane & 15)][ks * 32 + (lane >> 4) * 8]);
#pragma unroll
        for (int mt = 0; mt < 4; mt++)
#pragma unroll
            for (int et = 0; et < 4; et++)
                acc[mt][et] = __builtin_amdgcn_mfma_f32_16x16x32_bf16(af[mt], bfr[et], acc[mt][et], 0, 0, 0);
    }
    size_t abase = (size_t)b * 4096 + chunk * 256;
#pragma unroll
    for (int mt = 0; mt < 4; mt++) {
        int n = w * 64 + mt * 16 + ((lane >> 4) << 2);
#pragma unroll
        for (int et = 0; et < 4; et++) {
            int e = et * 16 + (lane & 15);
#pragma unroll
            for (int j = 0; j < 4; j++)
                attn[(abase + n + j) * 1024 + h * 64 + e] = f2bf(acc[mt][et][j]);
        }
    }
}

// ---------------- launch ----------------

extern "C" void kernel_launch(void* const* d_in, const int* in_sizes, int n_in,
                              void* d_out, int out_size, void* d_ws, size_t ws_size,
                              hipStream_t stream) {
    const float* x     = (const float*)d_in[0];
    const float* w_qkv = (const float*)d_in[1];
    const float* w_out = (const float*)d_in[2];
    const float* b_out = (const float*)d_in[3];
    float* out = (float*)d_out;
    char* ws = (char*)d_ws;

    // ws layout (bytes)
    size_t o_xb    = 0;                       // 16384*1024*2 = 33554432 (reused as attn)
    size_t o_wqkvT = 33554432;                // 3072*1024*2  = 6291456
    size_t o_woutT = 39845888;                // 1024*1024*2  = 2097152
    size_t o_qkv   = 41943040;                // 16384*3072*2 = 100663296
    size_t o_ctx   = 142606336;               // 64*64*64*4   = 1048576
    size_t o_pmax  = 143654912;               // 64*16*64*4   = 262144
    size_t o_psum  = 143917056;               // 262144
    size_t needed  = 144179200;
    if (ws_size < needed) return;             // visible failure if ws too small

    u16t* xb     = (u16t*)(ws + o_xb);
    u16t* attnb  = (u16t*)(ws + o_xb);        // reuse (xb dead after GEMM1)
    u16t* wqkvT  = (u16t*)(ws + o_wqkvT);
    u16t* woutT  = (u16t*)(ws + o_woutT);
    u16t* qkvb   = (u16t*)(ws + o_qkv);
    float* ctxT  = (float*)(ws + o_ctx);
    float* pmax  = (float*)(ws + o_pmax);
    float* psum  = (float*)(ws + o_psum);

    cvt_f32_bf16<<<2048, 256, 0, stream>>>(x, xb, 16777216);
    transpose_cvt<<<dim3(96, 32), dim3(32, 8), 0, stream>>>(w_qkv, wqkvT, 1024, 3072);
    transpose_cvt<<<dim3(32, 32), dim3(32, 8), 0, stream>>>(w_out, woutT, 1024, 1024);

    // GEMM1: [16384,1024] x [1024,3072] -> qkv ; grid 64*12 = 768 (div by 8)
    gemm256<0, 0><<<768, 512, 0, stream>>>(xb, wqkvT, qkvb, nullptr, 16384, 3072, 1024, 12);

    k_softmax_p1<<<dim3(64, 16), 256, 0, stream>>>(qkvb, pmax, psum);

    hipMemsetAsync(ctxT, 0, 64 * 64 * 64 * 4, stream);
    context_kernel<<<dim3(64, 8), 256, 0, stream>>>(qkvb, pmax, psum, ctxT);

    attn_gemm<<<dim3(64, 16), 256, 0, stream>>>(qkvb, ctxT, attnb);

    // GEMM2: [16384,1024] x [1024,1024] + bias -> out ; grid 64*4 = 256 (div by 8)
    gemm256<1, 1><<<256, 512, 0, stream>>>(attnb, woutT, out, b_out, 16384, 1024, 1024, 4);
}